// Round 2
// baseline (89.792 us; speedup 1.0000x reference)
//
#include <hip/hip_runtime.h>
#include <cstdint>
#include <cmath>

#define NN   4096
#define DXX  128
#define DD   64
#define KK   256
#define HH   256
#define DIN  192   // DD + DXX
#define ROWS 8

// ---------------- Threefry-2x32 (20 rounds), exact JAX semantics ----------------
__device__ __forceinline__ uint32_t rotl32(uint32_t v, uint32_t r){ return (v<<r)|(v>>(32u-r)); }

__device__ __forceinline__ void tf2x32(uint32_t k0, uint32_t k1,
                                       uint32_t x0, uint32_t x1,
                                       uint32_t& o0, uint32_t& o1){
  const uint32_t ks0=k0, ks1=k1, ks2 = k0 ^ k1 ^ 0x1BD11BDAu;
  x0 += ks0; x1 += ks1;
  // group 0: 13,15,26,6
  x0+=x1; x1=rotl32(x1,13); x1^=x0;
  x0+=x1; x1=rotl32(x1,15); x1^=x0;
  x0+=x1; x1=rotl32(x1,26); x1^=x0;
  x0+=x1; x1=rotl32(x1, 6); x1^=x0;
  x0+=ks1; x1+=ks2+1u;
  // group 1: 17,29,16,24
  x0+=x1; x1=rotl32(x1,17); x1^=x0;
  x0+=x1; x1=rotl32(x1,29); x1^=x0;
  x0+=x1; x1=rotl32(x1,16); x1^=x0;
  x0+=x1; x1=rotl32(x1,24); x1^=x0;
  x0+=ks2; x1+=ks0+2u;
  // group 2: 13,15,26,6
  x0+=x1; x1=rotl32(x1,13); x1^=x0;
  x0+=x1; x1=rotl32(x1,15); x1^=x0;
  x0+=x1; x1=rotl32(x1,26); x1^=x0;
  x0+=x1; x1=rotl32(x1, 6); x1^=x0;
  x0+=ks0; x1+=ks1+3u;
  // group 3: 17,29,16,24
  x0+=x1; x1=rotl32(x1,17); x1^=x0;
  x0+=x1; x1=rotl32(x1,29); x1^=x0;
  x0+=x1; x1=rotl32(x1,16); x1^=x0;
  x0+=x1; x1=rotl32(x1,24); x1^=x0;
  x0+=ks1; x1+=ks2+4u;
  // group 4: 13,15,26,6
  x0+=x1; x1=rotl32(x1,13); x1^=x0;
  x0+=x1; x1=rotl32(x1,15); x1^=x0;
  x0+=x1; x1=rotl32(x1,26); x1^=x0;
  x0+=x1; x1=rotl32(x1, 6); x1^=x0;
  x0+=ks2; x1+=ks0+5u;
  o0=x0; o1=x1;
}

// ---------------- mask dtype autodetect ----------------
__global__ void k_detect_mask(const uint32_t* __restrict__ mw, int nwords, int* __restrict__ flag){
  __shared__ int s;
  if (threadIdx.x==0) s=0;
  __syncthreads();
  int any=0;
  for (int i=threadIdx.x; i<nwords; i+=blockDim.x){
    uint32_t w = mw[i];
    if (w != 0u && w != 1u && w != 0x3F800000u) any = 1;
  }
  if (any) atomicOr(&s, 1);
  __syncthreads();
  if (threadIdx.x==0) *flag = s;
}

// ---------------- MLP layer 1: [zf, xt](N,192) @ W1(192,256) + b1, tanh ----------------
__global__ __launch_bounds__(256) void k_mlp1(const float* __restrict__ z, const float* __restrict__ xt,
                                              const float* __restrict__ W1, const float* __restrict__ b1,
                                              float* __restrict__ h1){
  const int n0 = blockIdx.x * ROWS;
  const int h  = threadIdx.x;
  __shared__ float row[ROWS][DIN];
  for (int i = h; i < ROWS*DIN; i += 256){
    int r = i / DIN, d = i % DIN;
    int n = n0 + r;
    float v;
    if (d < DD){ v = z[n*DD + d]; v = isfinite(v) ? v : 0.f; }
    else       { v = xt[n*DXX + (d-DD)]; }
    row[r][d] = v;
  }
  __syncthreads();
  float acc[ROWS];
  const float bb = b1[h];
  #pragma unroll
  for (int r=0;r<ROWS;++r) acc[r]=bb;
  for (int d=0; d<DIN; ++d){
    float w = W1[d*HH + h];
    #pragma unroll
    for (int r=0;r<ROWS;++r) acc[r] += row[r][d]*w;
  }
  #pragma unroll
  for (int r=0;r<ROWS;++r) h1[(size_t)(n0+r)*HH + h] = tanhf(acc[r]);
}

// ---------------- MLP layer 2 (in-place): h(N,256) @ W2(256,256) + b2, tanh ----------------
__global__ __launch_bounds__(256) void k_mlp2(float* __restrict__ hbuf, const float* __restrict__ W2,
                                              const float* __restrict__ b2){
  const int n0 = blockIdx.x * ROWS;
  const int t  = threadIdx.x;
  __shared__ float row[ROWS][HH];
  #pragma unroll
  for (int r=0;r<ROWS;++r) row[r][t] = hbuf[(size_t)(n0+r)*HH + t];
  __syncthreads();
  float acc[ROWS];
  const float bb = b2[t];
  #pragma unroll
  for (int r=0;r<ROWS;++r) acc[r]=bb;
  for (int d=0; d<HH; ++d){
    float w = W2[d*HH + t];
    #pragma unroll
    for (int r=0;r<ROWS;++r) acc[r] += row[r][d]*w;
  }
  #pragma unroll
  for (int r=0;r<ROWS;++r) hbuf[(size_t)(n0+r)*HH + t] = tanhf(acc[r]);
}

// ---------------- MLP layer 3: h(N,256) @ W3(256,64) + b3 ----------------
__global__ __launch_bounds__(64) void k_mlp3(const float* __restrict__ hbuf, const float* __restrict__ W3,
                                             const float* __restrict__ b3, float* __restrict__ gt){
  const int n0 = blockIdx.x * ROWS;
  const int t  = threadIdx.x;  // 0..63
  __shared__ float row[ROWS][HH];
  for (int i=t; i<ROWS*HH; i+=64){ int r=i/HH, d=i%HH; row[r][d] = hbuf[(size_t)(n0+r)*HH + d]; }
  __syncthreads();
  float acc[ROWS];
  const float bb = b3[t];
  #pragma unroll
  for (int r=0;r<ROWS;++r) acc[r]=bb;
  for (int d=0; d<HH; ++d){
    float w = W3[d*DD + t];
    #pragma unroll
    for (int r=0;r<ROWS;++r) acc[r] += row[r][d]*w;
  }
  #pragma unroll
  for (int r=0;r<ROWS;++r) gt[(size_t)(n0+r)*DD + t] = acc[r];
}

// ---------------- final: VQ argmin, prior, gumbel-categorical, outputs ----------------
__global__ __launch_bounds__(256) void k_final(
    const float* __restrict__ gt, const float* __restrict__ k_sample,
    const void* __restrict__ maskp, const float* __restrict__ transition,
    const float* __restrict__ start_pk, const float* __restrict__ C,
    const int* __restrict__ seedp, const int* __restrict__ flagp,
    float* __restrict__ out_z, float* __restrict__ out_kl,
    float* __restrict__ out_dkl, float* __restrict__ out_qk)
{
  const int n = blockIdx.x;
  const int k = threadIdx.x;   // 0..255
  __shared__ float sg[DD];
  __shared__ float sval[KK];
  __shared__ int   sidx[KK];
  __shared__ int   s_kidx;
  __shared__ float s_logp_qk;

  if (k < DD) sg[k] = gt[(size_t)n*DD + k];
  if (k == 0) s_kidx = 0;
  __syncthreads();

  const float ksv = k_sample[(size_t)n*KK + k];
  if (isfinite(ksv) && ksv > 0.5f) s_kidx = k;   // one-hot: single writer

  // VQ distance (argmin over sqrt'd values; sqrt monotone)
  float d2 = 0.f;
  const float* Ck = C + k*DD;
  #pragma unroll 8
  for (int d=0; d<DD; ++d){ float df = sg[d] - Ck[d]; d2 += df*df; }
  const float dist = sqrtf(d2);
  sval[k]=dist; sidx[k]=k;
  __syncthreads();
  const int kidx = s_kidx;
  for (int s=128; s>0; s>>=1){
    if (k<s){
      float v2=sval[k+s]; int i2=sidx[k+s];
      if (v2 < sval[k] || (v2 == sval[k] && i2 < sidx[k])){ sval[k]=v2; sidx[k]=i2; }
    }
    __syncthreads();
  }
  const int qk = sidx[0];
  __syncthreads();

  // prior row gather (k_sample exactly one-hot -> einsum == row gather)
  const float trow = transition[(size_t)n*(KK*KK) + (size_t)kidx*KK + k];
  sval[k] = trow;
  __syncthreads();
  for (int s=128; s>0; s>>=1){ if (k<s) sval[k]+=sval[k+s]; __syncthreads(); }
  const float tot = sval[0];
  __syncthreads();
  float pk = trow / tot;
  if (!isfinite(ksv)) pk = start_pk[(size_t)n*KK + k];
  const float logp = logf(pk);
  if (k == qk) s_logp_qk = logp;

  // ---- PARTITIONABLE threefry (modern JAX default) ----
  // split(key(seed),3) foldlike: k_rng = (o0,o1) of tf(key=(0,seed), counts=(0,0))
  // random_bits (N,K) u32: bits[i] = o0 ^ o1 of tf(k_rng, (hi32(i), lo32(i)))
  const uint32_t key1 = (uint32_t)seedp[0];
  uint32_t a0, a1;
  tf2x32(0u, key1, 0u, 0u, a0, a1);
  const uint32_t idx = (uint32_t)(n*KK + k);
  uint32_t o0, o1;
  tf2x32(a0, a1, 0u, idx, o0, o1);
  const uint32_t bits = o0 ^ o1;

  const float TINY = 1.17549435e-38f;
  const float f = __uint_as_float((bits>>9) | 0x3F800000u) - 1.0f;
  const float u = fmaxf(TINY, f + TINY);
  const float g = -logf(-logf(u));
  const float score = g + logp;
  sval[k]=score; sidx[k]=k;
  __syncthreads();
  for (int s=128; s>0; s>>=1){
    if (k<s){
      float v2=sval[k+s]; int i2=sidx[k+s];
      if (v2 > sval[k] || (v2 == sval[k] && i2 < sidx[k])){ sval[k]=v2; sidx[k]=i2; }
    }
    __syncthreads();
  }
  const int pkind = sidx[0];
  __syncthreads();

  // mask select (autodetected dtype: byte vs 4-byte word)
  bool m;
  if (*flagp) m = ((const unsigned char*)maskp)[n] != 0;
  else        m = ((const uint32_t*)maskp)[n] != 0u;  // int32 0/1 or f32 0.0/1.0 both OK
  const int sel = m ? qk : pkind;

  // z_new row + continuous KL
  float part = 0.f;
  if (k < DD){
    float c = C[sel*DD + k];
    out_z[(size_t)n*DD + k] = c;
    float df = sg[k] - c;
    part = df*df;
  }
  sval[k] = part;
  __syncthreads();
  for (int s=128; s>0; s>>=1){ if (k<s) sval[k]+=sval[k+s]; __syncthreads(); }
  if (k==0){
    float t = sqrtf(sval[0]);
    float kl = t + 0.25f*t;          // ||.|| + BETA*||.||, identical operands
    float dkl = -s_logp_qk;
    out_kl[n]  = kl + dkl;
    out_dkl[n] = dkl;
  }
  out_qk[(size_t)n*KK + k] = (k==qk) ? 1.0f : 0.0f;
}

extern "C" void kernel_launch(void* const* d_in, const int* in_sizes, int n_in,
                              void* d_out, int out_size, void* d_ws, size_t ws_size,
                              hipStream_t stream){
  const float* z    = (const float*)d_in[1];
  const float* ksm  = (const float*)d_in[2];
  const float* xt   = (const float*)d_in[3];
  const void*  mask = d_in[4];
  const float* tr   = (const float*)d_in[5];
  const float* spk  = (const float*)d_in[6];
  const float* W1   = (const float*)d_in[7];
  const float* b1   = (const float*)d_in[8];
  const float* W2   = (const float*)d_in[9];
  const float* b2   = (const float*)d_in[10];
  const float* W3   = (const float*)d_in[11];
  const float* b3   = (const float*)d_in[12];
  const float* C    = (const float*)d_in[13];
  const int*   seed = (const int*)d_in[14];

  float* bufA = (float*)d_ws;                    // N*H f32 (h1, then h2 in-place)
  float* gt   = bufA + (size_t)NN*HH;            // N*D f32
  int*   flag = (int*)(gt + (size_t)NN*DD);      // 1 int

  float* out_z   = (float*)d_out;                // N*D
  float* out_kl  = out_z   + (size_t)NN*DD;      // N
  float* out_dkl = out_kl  + NN;                 // N
  float* out_qk  = out_dkl + NN;                 // N*K

  k_detect_mask<<<1,256,0,stream>>>((const uint32_t*)mask, NN/4, flag);
  k_mlp1<<<NN/ROWS,256,0,stream>>>(z, xt, W1, b1, bufA);
  k_mlp2<<<NN/ROWS,256,0,stream>>>(bufA, W2, b2);
  k_mlp3<<<NN/ROWS, 64,0,stream>>>(bufA, W3, b3, gt);
  k_final<<<NN,256,0,stream>>>(gt, ksm, mask, tr, spk, C, seed, flag,
                               out_z, out_kl, out_dkl, out_qk);
}

// Round 3
// 69.081 us; speedup vs baseline: 1.2998x; 1.2998x over previous
//
#include <hip/hip_runtime.h>
#include <cstdint>
#include <cmath>

#define NN   4096
#define DXX  128
#define DD   64
#define KK   256
#define HH   256
#define DIN  192   // DD + DXX
#define ROWS 8
#define GRID (NN/ROWS)   // 512 blocks, 2 per CU

// ---------------- Threefry-2x32 (20 rounds), exact JAX semantics ----------------
__device__ __forceinline__ uint32_t rotl32(uint32_t v, uint32_t r){ return (v<<r)|(v>>(32u-r)); }

__device__ __forceinline__ void tf2x32(uint32_t k0, uint32_t k1,
                                       uint32_t x0, uint32_t x1,
                                       uint32_t& o0, uint32_t& o1){
  const uint32_t ks0=k0, ks1=k1, ks2 = k0 ^ k1 ^ 0x1BD11BDAu;
  x0 += ks0; x1 += ks1;
  x0+=x1; x1=rotl32(x1,13); x1^=x0;
  x0+=x1; x1=rotl32(x1,15); x1^=x0;
  x0+=x1; x1=rotl32(x1,26); x1^=x0;
  x0+=x1; x1=rotl32(x1, 6); x1^=x0;
  x0+=ks1; x1+=ks2+1u;
  x0+=x1; x1=rotl32(x1,17); x1^=x0;
  x0+=x1; x1=rotl32(x1,29); x1^=x0;
  x0+=x1; x1=rotl32(x1,16); x1^=x0;
  x0+=x1; x1=rotl32(x1,24); x1^=x0;
  x0+=ks2; x1+=ks0+2u;
  x0+=x1; x1=rotl32(x1,13); x1^=x0;
  x0+=x1; x1=rotl32(x1,15); x1^=x0;
  x0+=x1; x1=rotl32(x1,26); x1^=x0;
  x0+=x1; x1=rotl32(x1, 6); x1^=x0;
  x0+=ks0; x1+=ks1+3u;
  x0+=x1; x1=rotl32(x1,17); x1^=x0;
  x0+=x1; x1=rotl32(x1,29); x1^=x0;
  x0+=x1; x1=rotl32(x1,16); x1^=x0;
  x0+=x1; x1=rotl32(x1,24); x1^=x0;
  x0+=ks1; x1+=ks2+4u;
  x0+=x1; x1=rotl32(x1,13); x1^=x0;
  x0+=x1; x1=rotl32(x1,15); x1^=x0;
  x0+=x1; x1=rotl32(x1,26); x1^=x0;
  x0+=x1; x1=rotl32(x1, 6); x1^=x0;
  x0+=ks2; x1+=ks0+5u;
  o0=x0; o1=x1;
}

// ---------------- fused kernel: MLP + VQ + prior + categorical + outputs ----------------
__global__ __launch_bounds__(256,2) void k_fused(
    const float* __restrict__ z, const float* __restrict__ ks,
    const float* __restrict__ xt, const void* __restrict__ maskp,
    const float* __restrict__ tr, const float* __restrict__ spk,
    const float* __restrict__ W1, const float* __restrict__ b1,
    const float* __restrict__ W2, const float* __restrict__ b2,
    const float* __restrict__ W3, const float* __restrict__ b3,
    const float* __restrict__ Cg, const int* __restrict__ seedp,
    float* __restrict__ out_z, float* __restrict__ out_kl,
    float* __restrict__ out_dkl, float* __restrict__ out_qk)
{
  const int t  = threadIdx.x;
  const int n0 = blockIdx.x * ROWS;

  __shared__ float in_s[ROWS][DIN];
  __shared__ __align__(16) float row[ROWS][HH];
  __shared__ float sgt[ROWS][DD];
  __shared__ float stg[DD][65];      // C transpose staging chunk (64 codes x 64 d, padded)
  __shared__ float rv[2][4];
  __shared__ int   ri[3][4];
  __shared__ float rs[4];
  __shared__ float sh_logqk;
  __shared__ int   sh_flag;

  // ---- mask dtype autodetect (block-local; first 1024 words cover both layouts) ----
  if (t==0) sh_flag = 0;
  __syncthreads();
  {
    const uint32_t* mw = (const uint32_t*)maskp;
    uint32_t bad = 0;
    #pragma unroll
    for (int q=0;q<4;++q){
      uint32_t w = mw[t + q*256];
      if (w!=0u && w!=1u && w!=0x3F800000u) bad = 1;
    }
    if (bad) atomicOr(&sh_flag, 1);
  }

  // ---- MLP layer 1 input staging ----
  for (int i=t; i<ROWS*DIN; i+=256){
    int r=i/DIN, d=i%DIN; int n=n0+r; float v;
    if (d<DD){ v = z[(size_t)n*DD+d]; if(!isfinite(v)) v = 0.f; }
    else     { v = xt[(size_t)n*DXX + (d-DD)]; }
    in_s[r][d] = v;
  }
  __syncthreads();

  float acc[ROWS];
  // ---- MLP1: tanh([z,x] @ W1 + b1) ----
  {
    const float bb = b1[t];
    #pragma unroll
    for (int r=0;r<ROWS;++r) acc[r]=bb;
    for (int d=0; d<DIN; ++d){
      float w = W1[d*HH + t];
      #pragma unroll
      for (int r=0;r<ROWS;++r) acc[r] += in_s[r][d]*w;
    }
    #pragma unroll
    for (int r=0;r<ROWS;++r) row[r][t] = tanhf(acc[r]);
  }
  __syncthreads();
  // ---- MLP2: tanh(h @ W2 + b2) ----
  {
    const float bb = b2[t];
    #pragma unroll
    for (int r=0;r<ROWS;++r) acc[r]=bb;
    for (int d=0; d<HH; ++d){
      float w = W2[d*HH + t];
      #pragma unroll
      for (int r=0;r<ROWS;++r) acc[r] += row[r][d]*w;
    }
  }
  __syncthreads();   // all h1 reads complete before overwrite
  #pragma unroll
  for (int r=0;r<ROWS;++r) row[r][t] = tanhf(acc[r]);
  __syncthreads();
  // ---- MLP3: gt = h2 @ W3 + b3 -> sgt (LDS only) ----
  {
    const int g = t>>6, d = t&63;
    const int r0 = g, r1 = g+4;
    float a0 = b3[d], a1 = b3[d];
    for (int dp=0; dp<HH; dp+=4){
      float w0 = W3[(dp+0)*DD + d];
      float w1 = W3[(dp+1)*DD + d];
      float w2 = W3[(dp+2)*DD + d];
      float w3 = W3[(dp+3)*DD + d];
      float4 h0 = *(const float4*)&row[r0][dp];
      float4 h1 = *(const float4*)&row[r1][dp];
      a0 += h0.x*w0; a0 += h0.y*w1; a0 += h0.z*w2; a0 += h0.w*w3;
      a1 += h1.x*w0; a1 += h1.y*w1; a1 += h1.z*w2; a1 += h1.w*w3;
    }
    sgt[r0][d] = a0; sgt[r1][d] = a1;
  }

  // ---- codebook -> registers (coalesced load, LDS transpose, 4 chunks) ----
  float creg[DD];
  #pragma unroll 1
  for (int c=0;c<4;++c){
    __syncthreads();                               // protect stg reuse (also fences sgt/flag)
    #pragma unroll
    for (int q=0;q<4;++q){
      int f = q*256 + t;                           // float4 index within chunk
      float4 v = ((const float4*)Cg)[c*1024 + f];
      int cl = f>>4, d0 = (f&15)*4;
      stg[cl][d0+0]=v.x; stg[cl][d0+1]=v.y; stg[cl][d0+2]=v.z; stg[cl][d0+3]=v.w;
    }
    __syncthreads();
    if ((t>>6)==c){
      const int l = t&63;
      #pragma unroll
      for (int d=0; d<DD; ++d) creg[d] = stg[l][d];
    }
  }
  __syncthreads();

  const int flag = sh_flag;
  uint32_t ka0, ka1;
  tf2x32(0u, (uint32_t)seedp[0], 0u, 0u, ka0, ka1);   // partitionable split: k_rng

  // ---- per-row finalization ----
  #pragma unroll 1
  for (int r=0; r<ROWS; ++r){
    const int n = n0 + r;
    const float ksv = ks[(size_t)n*KK + t];

    // carry index (one-hot argmax) via block min
    int kv = (isfinite(ksv) && ksv > 0.5f) ? t : 0x7fffffff;
    #pragma unroll
    for (int m=32;m;m>>=1){ int o=__shfl_xor(kv,m,64); if (o<kv) kv=o; }
    if ((t&63)==0) ri[0][t>>6]=kv;
    __syncthreads();                                  // B1
    { int v0=ri[0][0]; if(ri[0][1]<v0)v0=ri[0][1]; if(ri[0][2]<v0)v0=ri[0][2]; if(ri[0][3]<v0)v0=ri[0][3]; kv=v0; }
    const int kidx = kv;

    const float trow = tr[(size_t)n*(KK*KK) + (size_t)kidx*KK + t];  // issue early

    // VQ distance: sequential d accumulation (bit-identical to ref order)
    float d2 = 0.f;
    #pragma unroll
    for (int d=0; d<DD; ++d){ float df = sgt[r][d] - creg[d]; d2 += df*df; }
    float dv = sqrtf(d2); int di = t;
    #pragma unroll
    for (int m=32;m;m>>=1){
      float ov=__shfl_xor(dv,m,64); int oi=__shfl_xor(di,m,64);
      if (ov<dv || (ov==dv && oi<di)){ dv=ov; di=oi; }
    }
    if ((t&63)==0){ rv[0][t>>6]=dv; ri[1][t>>6]=di; }
    __syncthreads();                                  // B2
    { float bv=rv[0][0]; int bi=ri[1][0];
      #pragma unroll
      for (int w=1;w<4;++w){ float ov=rv[0][w]; int oi=ri[1][w];
        if (ov<bv || (ov==bv && oi<bi)){ bv=ov; bi=oi; } }
      di = bi; }
    const int qk = di;

    // prior normalization
    float s = trow;
    #pragma unroll
    for (int m=32;m;m>>=1) s += __shfl_xor(s,m,64);
    if ((t&63)==0) rs[t>>6]=s;
    __syncthreads();                                  // B3
    const float tot = ((rs[0]+rs[1])+rs[2])+rs[3];
    float pk = trow / tot;
    if (!isfinite(ksv)) pk = spk[(size_t)n*KK + t];
    const float logp = logf(pk);
    if (t == qk) sh_logqk = logp;

    // mask (uniform per row)
    bool m;
    if (flag) m = ((const unsigned char*)maskp)[n] != 0;
    else      m = ((const uint32_t*)maskp)[n] != 0u;

    int sel;
    if (m){
      __syncthreads();                                // B4 (fence sh_logqk)
      sel = qk;
    } else {
      // gumbel-max categorical (partitionable threefry bits)
      uint32_t o0,o1; tf2x32(ka0, ka1, 0u, (uint32_t)(n*KK + t), o0, o1);
      const uint32_t bits = o0 ^ o1;
      const float TINY = 1.17549435e-38f;
      const float f = __uint_as_float((bits>>9) | 0x3F800000u) - 1.0f;
      const float u = fmaxf(TINY, f + TINY);
      const float g = -logf(-logf(u));
      float sc = g + logp; int si = t;
      #pragma unroll
      for (int mm=32;mm;mm>>=1){
        float ov=__shfl_xor(sc,mm,64); int oi=__shfl_xor(si,mm,64);
        if (ov>sc || (ov==sc && oi<si)){ sc=ov; si=oi; }
      }
      if ((t&63)==0){ rv[1][t>>6]=sc; ri[2][t>>6]=si; }
      __syncthreads();                                // B4
      float bv=rv[1][0]; int bi=ri[2][0];
      #pragma unroll
      for (int w=1;w<4;++w){ float ov=rv[1][w]; int oi=ri[2][w];
        if (ov>bv || (ov==bv && oi<bi)){ bv=ov; bi=oi; } }
      sel = bi;
    }

    out_qk[(size_t)n*KK + t] = (t==qk) ? 1.0f : 0.0f;
    if (t < DD){
      const float c = Cg[(size_t)sel*DD + t];
      out_z[(size_t)n*DD + t] = c;
      float df = sgt[r][t] - c;
      float p = df*df;
      #pragma unroll
      for (int mm=32;mm;mm>>=1) p += __shfl_xor(p,mm,64);
      if (t==0){
        const float tt  = sqrtf(p);
        const float dkl = -sh_logqk;
        out_kl[n]  = (tt + 0.25f*tt) + dkl;
        out_dkl[n] = dkl;
      }
    }
  }
}

extern "C" void kernel_launch(void* const* d_in, const int* in_sizes, int n_in,
                              void* d_out, int out_size, void* d_ws, size_t ws_size,
                              hipStream_t stream){
  const float* z    = (const float*)d_in[1];
  const float* ksm  = (const float*)d_in[2];
  const float* xt   = (const float*)d_in[3];
  const void*  mask = d_in[4];
  const float* tr   = (const float*)d_in[5];
  const float* spk  = (const float*)d_in[6];
  const float* W1   = (const float*)d_in[7];
  const float* b1   = (const float*)d_in[8];
  const float* W2   = (const float*)d_in[9];
  const float* b2   = (const float*)d_in[10];
  const float* W3   = (const float*)d_in[11];
  const float* b3   = (const float*)d_in[12];
  const float* C    = (const float*)d_in[13];
  const int*   seed = (const int*)d_in[14];

  float* out_z   = (float*)d_out;                // N*D
  float* out_kl  = out_z   + (size_t)NN*DD;      // N
  float* out_dkl = out_kl  + NN;                 // N
  float* out_qk  = out_dkl + NN;                 // N*K

  k_fused<<<GRID,256,0,stream>>>(z, ksm, xt, mask, tr, spk,
                                 W1, b1, W2, b2, W3, b3, C, seed,
                                 out_z, out_kl, out_dkl, out_qk);
}

// Round 4
// 54.785 us; speedup vs baseline: 1.6390x; 1.2610x over previous
//
#include <hip/hip_runtime.h>
#include <cstdint>
#include <cmath>

#define NN   4096
#define DXX  128
#define DD   64
#define KK   256
#define HH   256
#define DIN  192   // DD + DXX
#define ROWS 8
#define GRID (NN/ROWS)   // 512 blocks, 2 per CU

// ---------------- Threefry-2x32 (20 rounds), exact JAX semantics ----------------
__device__ __forceinline__ uint32_t rotl32(uint32_t v, uint32_t r){ return (v<<r)|(v>>(32u-r)); }

__device__ __forceinline__ void tf2x32(uint32_t k0, uint32_t k1,
                                       uint32_t x0, uint32_t x1,
                                       uint32_t& o0, uint32_t& o1){
  const uint32_t ks0=k0, ks1=k1, ks2 = k0 ^ k1 ^ 0x1BD11BDAu;
  x0 += ks0; x1 += ks1;
  x0+=x1; x1=rotl32(x1,13); x1^=x0;
  x0+=x1; x1=rotl32(x1,15); x1^=x0;
  x0+=x1; x1=rotl32(x1,26); x1^=x0;
  x0+=x1; x1=rotl32(x1, 6); x1^=x0;
  x0+=ks1; x1+=ks2+1u;
  x0+=x1; x1=rotl32(x1,17); x1^=x0;
  x0+=x1; x1=rotl32(x1,29); x1^=x0;
  x0+=x1; x1=rotl32(x1,16); x1^=x0;
  x0+=x1; x1=rotl32(x1,24); x1^=x0;
  x0+=ks2; x1+=ks0+2u;
  x0+=x1; x1=rotl32(x1,13); x1^=x0;
  x0+=x1; x1=rotl32(x1,15); x1^=x0;
  x0+=x1; x1=rotl32(x1,26); x1^=x0;
  x0+=x1; x1=rotl32(x1, 6); x1^=x0;
  x0+=ks0; x1+=ks1+3u;
  x0+=x1; x1=rotl32(x1,17); x1^=x0;
  x0+=x1; x1=rotl32(x1,29); x1^=x0;
  x0+=x1; x1=rotl32(x1,16); x1^=x0;
  x0+=x1; x1=rotl32(x1,24); x1^=x0;
  x0+=ks1; x1+=ks2+4u;
  x0+=x1; x1=rotl32(x1,13); x1^=x0;
  x0+=x1; x1=rotl32(x1,15); x1^=x0;
  x0+=x1; x1=rotl32(x1,26); x1^=x0;
  x0+=x1; x1=rotl32(x1, 6); x1^=x0;
  x0+=ks2; x1+=ks0+5u;
  o0=x0; o1=x1;
}

__device__ __forceinline__ float gumbel_of(uint32_t ka0, uint32_t ka1, uint32_t idx){
  uint32_t o0,o1; tf2x32(ka0,ka1,0u,idx,o0,o1);
  const uint32_t bits = o0 ^ o1;
  const float TINY = 1.17549435e-38f;
  const float f = __uint_as_float((bits>>9) | 0x3F800000u) - 1.0f;
  const float u = fmaxf(TINY, f + TINY);
  return -logf(-logf(u));
}

// ---------------- fused kernel ----------------
__global__ __launch_bounds__(256,2) void k_fused(
    const float* __restrict__ z, const float* __restrict__ ks,
    const float* __restrict__ xt, const void* __restrict__ maskp,
    const float* __restrict__ tr, const float* __restrict__ spk,
    const float* __restrict__ W1, const float* __restrict__ b1,
    const float* __restrict__ W2, const float* __restrict__ b2,
    const float* __restrict__ W3, const float* __restrict__ b3,
    const float* __restrict__ Cg, const int* __restrict__ seedp,
    float* __restrict__ out_z, float* __restrict__ out_kl,
    float* __restrict__ out_dkl, float* __restrict__ out_qk)
{
  const int t    = threadIdx.x;
  const int lane = t & 63;
  const int wv   = t >> 6;              // wave id 0..3
  const int n0   = blockIdx.x * ROWS;

  // LDS overlay: [0,6144) in_s | [6144,14336) row | sdist overlays [0,8192)
  // (row/in_s dead after MLP3) | [14336,30976) stg
  __shared__ __align__(16) char smem[30976];
  float (*in_s)[DIN] = (float(*)[DIN]) smem;
  float (*row)[HH]   = (float(*)[HH]) (smem + 6144);
  float (*sdist)[KK] = (float(*)[KK]) smem;
  float (*stg)[65]   = (float(*)[65]) (smem + 14336);
  __shared__ __align__(16) float sgt[ROWS][DD];
  __shared__ int sh_flag;

  // ---- prefetch this wave's two k_sample rows (latency hidden under MLP) ----
  const int nA = n0 + wv, nB = n0 + wv + 4;
  const float4 ksA = ((const float4*)ks)[(size_t)nA*(KK/4) + lane];
  const float4 ksB = ((const float4*)ks)[(size_t)nB*(KK/4) + lane];

  // ---- mask dtype autodetect ----
  if (t==0) sh_flag = 0;
  __syncthreads();
  {
    const uint32_t* mw = (const uint32_t*)maskp;
    uint32_t bad=0;
    #pragma unroll
    for (int q=0;q<4;++q){ uint32_t wd=mw[t+q*256]; if (wd!=0u && wd!=1u && wd!=0x3F800000u) bad=1; }
    if (bad) atomicOr(&sh_flag,1);
  }

  // ---- MLP input staging ----
  for (int i=t; i<ROWS*DIN; i+=256){
    int r=i/DIN, d=i%DIN; int n=n0+r; float v;
    if (d<DD){ v = z[(size_t)n*DD+d]; if(!isfinite(v)) v=0.f; }
    else     { v = xt[(size_t)n*DXX + (d-DD)]; }
    in_s[r][d] = v;
  }
  __syncthreads();

  float acc[ROWS];
  // ---- MLP1 ----
  {
    const float bb = b1[t];
    #pragma unroll
    for (int r=0;r<ROWS;++r) acc[r]=bb;
    for (int d4=0; d4<DIN; d4+=4){
      float w0=W1[(d4+0)*HH+t], w1=W1[(d4+1)*HH+t], w2=W1[(d4+2)*HH+t], w3=W1[(d4+3)*HH+t];
      #pragma unroll
      for (int r=0;r<ROWS;++r){
        float4 a = *(const float4*)&in_s[r][d4];
        acc[r]+=a.x*w0; acc[r]+=a.y*w1; acc[r]+=a.z*w2; acc[r]+=a.w*w3;
      }
    }
    #pragma unroll
    for (int r=0;r<ROWS;++r) row[r][t] = tanhf(acc[r]);
  }
  __syncthreads();
  // ---- MLP2 ----
  {
    const float bb = b2[t];
    #pragma unroll
    for (int r=0;r<ROWS;++r) acc[r]=bb;
    for (int d4=0; d4<HH; d4+=4){
      float w0=W2[(d4+0)*HH+t], w1=W2[(d4+1)*HH+t], w2=W2[(d4+2)*HH+t], w3=W2[(d4+3)*HH+t];
      #pragma unroll
      for (int r=0;r<ROWS;++r){
        float4 a = *(const float4*)&row[r][d4];
        acc[r]+=a.x*w0; acc[r]+=a.y*w1; acc[r]+=a.z*w2; acc[r]+=a.w*w3;
      }
    }
  }
  __syncthreads();
  #pragma unroll
  for (int r=0;r<ROWS;++r) row[r][t] = tanhf(acc[r]);
  __syncthreads();
  // ---- MLP3 -> sgt ----
  {
    const int g=t>>6, d=t&63;
    const int r0=g, r1=g+4;
    float a0=b3[d], a1=b3[d];
    for (int dp=0; dp<HH; dp+=4){
      float w0=W3[(dp+0)*DD+d], w1=W3[(dp+1)*DD+d], w2=W3[(dp+2)*DD+d], w3=W3[(dp+3)*DD+d];
      float4 h0=*(const float4*)&row[r0][dp];
      float4 h1=*(const float4*)&row[r1][dp];
      a0+=h0.x*w0; a0+=h0.y*w1; a0+=h0.z*w2; a0+=h0.w*w3;
      a1+=h1.x*w0; a1+=h1.y*w1; a1+=h1.z*w2; a1+=h1.w*w3;
    }
    sgt[r0][d]=a0; sgt[r1][d]=a1;
  }

  // ---- codebook -> registers (coalesced, LDS transpose, 4 chunks) ----
  float creg[DD];
  #pragma unroll 1
  for (int c=0;c<4;++c){
    __syncthreads();
    #pragma unroll
    for (int q=0;q<4;++q){
      int f=q*256+t;
      float4 v=((const float4*)Cg)[c*1024+f];
      int cl=f>>4, d0=(f&15)*4;
      stg[cl][d0+0]=v.x; stg[cl][d0+1]=v.y; stg[cl][d0+2]=v.z; stg[cl][d0+3]=v.w;
    }
    __syncthreads();
    if ((t>>6)==c){
      #pragma unroll
      for (int d=0;d<DD;++d) creg[d]=stg[lane][d];
    }
  }
  __syncthreads();

  // ---- distances for all 8 rows (thread t owns code t; order == round-3) ----
  #pragma unroll 1
  for (int r=0;r<ROWS;++r){
    float d2=0.f;
    #pragma unroll
    for (int d4=0; d4<DD; d4+=4){
      float4 s4 = *(const float4*)&sgt[r][d4];
      float df;
      df=s4.x-creg[d4+0]; d2+=df*df;
      df=s4.y-creg[d4+1]; d2+=df*df;
      df=s4.z-creg[d4+2]; d2+=df*df;
      df=s4.w-creg[d4+3]; d2+=df*df;
    }
    sdist[r][t]=sqrtf(d2);
  }
  __syncthreads();

  // ---- wave-local finalize: wave wv owns rows wv and wv+4, no barriers ----
  const int flag = sh_flag;
  uint32_t ka0,ka1;
  tf2x32(0u,(uint32_t)seedp[0],0u,0u,ka0,ka1);   // partitionable split: k_rng

  auto kidx_of=[&](const float4& kq)->int{
    int kv=0x7fffffff;
    if (isfinite(kq.x)&&kq.x>0.5f) kv=4*lane+0;
    if (isfinite(kq.y)&&kq.y>0.5f&&4*lane+1<kv) kv=4*lane+1;
    if (isfinite(kq.z)&&kq.z>0.5f&&4*lane+2<kv) kv=4*lane+2;
    if (isfinite(kq.w)&&kq.w>0.5f&&4*lane+3<kv) kv=4*lane+3;
    unsigned long long bl=__ballot(kv!=0x7fffffff);
    if (bl){ int src=(int)__builtin_ctzll(bl); kv=__shfl(kv,src,64); }
    else kv=0;
    return kv;
  };
  const int kA=kidx_of(ksA), kB=kidx_of(ksB);
  const float4 trA=((const float4*)tr)[(size_t)nA*(KK*KK/4)+(size_t)kA*(KK/4)+lane];
  const float4 trB=((const float4*)tr)[(size_t)nB*(KK*KK/4)+(size_t)kB*(KK/4)+lane];

  auto process=[&](int n,int r,const float4& ksq,const float4& trq){
    // VQ argmin (first-index tie-break)
    float4 dq = *(const float4*)&sdist[r][4*lane];
    float dv=dq.x; int di=4*lane;
    if (dq.y<dv){dv=dq.y;di=4*lane+1;}
    if (dq.z<dv){dv=dq.z;di=4*lane+2;}
    if (dq.w<dv){dv=dq.w;di=4*lane+3;}
    #pragma unroll
    for (int m=32;m;m>>=1){
      float ov=__shfl_xor(dv,m,64); int oi=__shfl_xor(di,m,64);
      if (ov<dv||(ov==dv&&oi<di)){dv=ov;di=oi;}
    }
    const int qk=di;

    // prior normalization
    float s=((trq.x+trq.y)+trq.z)+trq.w;
    #pragma unroll
    for (int m=32;m;m>>=1) s+=__shfl_xor(s,m,64);
    float p0=trq.x/s, p1=trq.y/s, p2=trq.z/s, p3=trq.w/s;
    bool f0=isfinite(ksq.x),f1=isfinite(ksq.y),f2=isfinite(ksq.z),f3=isfinite(ksq.w);
    if (__any(!(f0&&f1&&f2&&f3))){
      float4 sq=((const float4*)spk)[(size_t)n*(KK/4)+lane];
      if(!f0)p0=sq.x; if(!f1)p1=sq.y; if(!f2)p2=sq.z; if(!f3)p3=sq.w;
    }
    const float lp0=logf(p0), lp1=logf(p1), lp2=logf(p2), lp3=logf(p3);
    const int jq=qk&3;
    float lps=(jq==0)?lp0:((jq==1)?lp1:((jq==2)?lp2:lp3));
    const float logqk=__shfl(lps,qk>>2,64);

    // mask (uniform per row)
    bool m;
    if (flag) m=((const unsigned char*)maskp)[n]!=0;
    else      m=((const uint32_t*)maskp)[n]!=0u;

    int sel;
    if (m){ sel=qk; }
    else {
      float sc=gumbel_of(ka0,ka1,(uint32_t)(n*KK+4*lane+0))+lp0; int si=4*lane;
      { float g=gumbel_of(ka0,ka1,(uint32_t)(n*KK+4*lane+1))+lp1; if(g>sc){sc=g;si=4*lane+1;} }
      { float g=gumbel_of(ka0,ka1,(uint32_t)(n*KK+4*lane+2))+lp2; if(g>sc){sc=g;si=4*lane+2;} }
      { float g=gumbel_of(ka0,ka1,(uint32_t)(n*KK+4*lane+3))+lp3; if(g>sc){sc=g;si=4*lane+3;} }
      #pragma unroll
      for (int mm=32;mm;mm>>=1){
        float ov=__shfl_xor(sc,mm,64); int oi=__shfl_xor(si,mm,64);
        if (ov>sc||(ov==sc&&oi<si)){sc=ov;si=oi;}
      }
      sel=si;
    }

    ((float4*)out_qk)[(size_t)n*(KK/4)+lane]=make_float4(
      (4*lane+0==qk)?1.f:0.f,(4*lane+1==qk)?1.f:0.f,
      (4*lane+2==qk)?1.f:0.f,(4*lane+3==qk)?1.f:0.f);

    const float c=Cg[(size_t)sel*DD+lane];
    out_z[(size_t)n*DD+lane]=c;
    float df=sgt[r][lane]-c;
    float p=df*df;
    #pragma unroll
    for (int mm=32;mm;mm>>=1) p+=__shfl_xor(p,mm,64);
    if (lane==0){
      float tt=sqrtf(p);
      float dkl=-logqk;
      out_kl[n]=(tt+0.25f*tt)+dkl;
      out_dkl[n]=dkl;
    }
  };
  process(nA,wv,ksA,trA);
  process(nB,wv+4,ksB,trB);
}

extern "C" void kernel_launch(void* const* d_in, const int* in_sizes, int n_in,
                              void* d_out, int out_size, void* d_ws, size_t ws_size,
                              hipStream_t stream){
  const float* z    = (const float*)d_in[1];
  const float* ksm  = (const float*)d_in[2];
  const float* xt   = (const float*)d_in[3];
  const void*  mask = d_in[4];
  const float* tr   = (const float*)d_in[5];
  const float* spk  = (const float*)d_in[6];
  const float* W1   = (const float*)d_in[7];
  const float* b1   = (const float*)d_in[8];
  const float* W2   = (const float*)d_in[9];
  const float* b2   = (const float*)d_in[10];
  const float* W3   = (const float*)d_in[11];
  const float* b3   = (const float*)d_in[12];
  const float* C    = (const float*)d_in[13];
  const int*   seed = (const int*)d_in[14];

  float* out_z   = (float*)d_out;                // N*D
  float* out_kl  = out_z   + (size_t)NN*DD;      // N
  float* out_dkl = out_kl  + NN;                 // N
  float* out_qk  = out_dkl + NN;                 // N*K

  k_fused<<<GRID,256,0,stream>>>(z, ksm, xt, mask, tr, spk,
                                 W1, b1, W2, b2, W3, b3, C, seed,
                                 out_z, out_kl, out_dkl, out_qk);
}

// Round 5
// 53.822 us; speedup vs baseline: 1.6683x; 1.0179x over previous
//
#include <hip/hip_runtime.h>
#include <cstdint>
#include <cmath>

#define NN   4096
#define DXX  128
#define DD   64
#define KK   256
#define HH   256
#define DIN  192   // DD + DXX
#define ROWS 8
#define NT   512
#define GRID (NN/ROWS)   // 512 blocks, 2 per CU (8 waves each -> 4 waves/SIMD)

// ---------------- Threefry-2x32 (20 rounds), exact JAX semantics ----------------
__device__ __forceinline__ uint32_t rotl32(uint32_t v, uint32_t r){ return (v<<r)|(v>>(32u-r)); }

__device__ __forceinline__ void tf2x32(uint32_t k0, uint32_t k1,
                                       uint32_t x0, uint32_t x1,
                                       uint32_t& o0, uint32_t& o1){
  const uint32_t ks0=k0, ks1=k1, ks2 = k0 ^ k1 ^ 0x1BD11BDAu;
  x0 += ks0; x1 += ks1;
  x0+=x1; x1=rotl32(x1,13); x1^=x0;
  x0+=x1; x1=rotl32(x1,15); x1^=x0;
  x0+=x1; x1=rotl32(x1,26); x1^=x0;
  x0+=x1; x1=rotl32(x1, 6); x1^=x0;
  x0+=ks1; x1+=ks2+1u;
  x0+=x1; x1=rotl32(x1,17); x1^=x0;
  x0+=x1; x1=rotl32(x1,29); x1^=x0;
  x0+=x1; x1=rotl32(x1,16); x1^=x0;
  x0+=x1; x1=rotl32(x1,24); x1^=x0;
  x0+=ks2; x1+=ks0+2u;
  x0+=x1; x1=rotl32(x1,13); x1^=x0;
  x0+=x1; x1=rotl32(x1,15); x1^=x0;
  x0+=x1; x1=rotl32(x1,26); x1^=x0;
  x0+=x1; x1=rotl32(x1, 6); x1^=x0;
  x0+=ks0; x1+=ks1+3u;
  x0+=x1; x1=rotl32(x1,17); x1^=x0;
  x0+=x1; x1=rotl32(x1,29); x1^=x0;
  x0+=x1; x1=rotl32(x1,16); x1^=x0;
  x0+=x1; x1=rotl32(x1,24); x1^=x0;
  x0+=ks1; x1+=ks2+4u;
  x0+=x1; x1=rotl32(x1,13); x1^=x0;
  x0+=x1; x1=rotl32(x1,15); x1^=x0;
  x0+=x1; x1=rotl32(x1,26); x1^=x0;
  x0+=x1; x1=rotl32(x1, 6); x1^=x0;
  x0+=ks2; x1+=ks0+5u;
  o0=x0; o1=x1;
}

__device__ __forceinline__ float gumbel_of(uint32_t ka0, uint32_t ka1, uint32_t idx){
  uint32_t o0,o1; tf2x32(ka0,ka1,0u,idx,o0,o1);
  const uint32_t bits = o0 ^ o1;
  const float TINY = 1.17549435e-38f;
  const float f = __uint_as_float((bits>>9) | 0x3F800000u) - 1.0f;
  const float u = fmaxf(TINY, f + TINY);
  return -logf(-logf(u));
}

// LDS layout (bytes):
// [0,6144)      in_s[8][192]
// [6144,14336)  row [8][256]   (h1)
// [14336,22528) row2[8][256]   (h2)
// [22528,24576) sgt [8][64]
// [24576,41216) stg[64][65]  -- codebook transpose chunk; overlaid later by
//               spart[2][8][256] (16384 B) for distance partials
#define OFF_ROW   6144
#define OFF_ROW2  14336
#define OFF_SGT   22528
#define OFF_STG   24576

__global__ __launch_bounds__(NT,4) void k_fused(
    const float* __restrict__ z, const float* __restrict__ ks,
    const float* __restrict__ xt, const void* __restrict__ maskp,
    const float* __restrict__ tr, const float* __restrict__ spk,
    const float* __restrict__ W1, const float* __restrict__ b1,
    const float* __restrict__ W2, const float* __restrict__ b2,
    const float* __restrict__ W3, const float* __restrict__ b3,
    const float* __restrict__ Cg, const int* __restrict__ seedp,
    float* __restrict__ out_z, float* __restrict__ out_kl,
    float* __restrict__ out_dkl, float* __restrict__ out_qk)
{
  const int t    = threadIdx.x;
  const int lane = t & 63;
  const int wv   = t >> 6;          // wave 0..7
  const int col  = t & 255;         // MLP1/2 output column
  const int rh   = t >> 8;          // row half (0/1)
  const int r0   = rh * 4;
  const int n0   = blockIdx.x * ROWS;
  const int nw   = n0 + wv;         // finalize: wave wv owns row nw

  __shared__ __align__(16) char smem[41216];
  float (*in_s)[DIN] = (float(*)[DIN]) smem;
  float (*row )[HH]  = (float(*)[HH]) (smem + OFF_ROW);
  float (*row2)[HH]  = (float(*)[HH]) (smem + OFF_ROW2);
  float (*sgt )[DD]  = (float(*)[DD]) (smem + OFF_SGT);
  float (*stg )[65]  = (float(*)[65]) (smem + OFF_STG);
  float *sp          = (float*)       (smem + OFF_STG);   // spart overlay
  __shared__ int sh_flag;

  // ---- prefetch this wave's k_sample row (latency hidden under MLP) ----
  const float4 ksq = ((const float4*)ks)[(size_t)nw*(KK/4) + lane];

  // ---- mask dtype autodetect ----
  if (t==0) sh_flag = 0;
  __syncthreads();
  {
    const uint32_t* mw = (const uint32_t*)maskp;
    uint32_t bad=0;
    #pragma unroll
    for (int q=0;q<2;++q){ uint32_t wd=mw[t+q*NT]; if (wd!=0u && wd!=1u && wd!=0x3F800000u) bad=1; }
    if (bad) atomicOr(&sh_flag,1);
  }

  // ---- MLP input staging ----
  for (int i=t; i<ROWS*DIN; i+=NT){
    int r=i/DIN, d=i%DIN; int n=n0+r; float v;
    if (d<DD){ v = z[(size_t)n*DD+d]; if(!isfinite(v)) v=0.f; }
    else     { v = xt[(size_t)n*DXX + (d-DD)]; }
    in_s[r][d] = v;
  }
  __syncthreads();

  float a0,a1,a2,a3;
  // ================= MLP1: tanh([z,x]@W1+b1), prefetched =================
  {
    const float bb = b1[col];
    a0=bb; a1=bb; a2=bb; a3=bb;
    float w0=W1[0*HH+col], w1=W1[1*HH+col], w2=W1[2*HH+col], w3=W1[3*HH+col];
    int d4=0;
    for (;;){
      const bool last = (d4+4>=DIN);
      float nw0,nw1,nw2,nw3;
      if (!last){
        nw0=W1[(d4+4)*HH+col]; nw1=W1[(d4+5)*HH+col];
        nw2=W1[(d4+6)*HH+col]; nw3=W1[(d4+7)*HH+col];
      }
      float4 x0=*(const float4*)&in_s[r0+0][d4];
      float4 x1=*(const float4*)&in_s[r0+1][d4];
      float4 x2=*(const float4*)&in_s[r0+2][d4];
      float4 x3=*(const float4*)&in_s[r0+3][d4];
      a0+=x0.x*w0; a0+=x0.y*w1; a0+=x0.z*w2; a0+=x0.w*w3;
      a1+=x1.x*w0; a1+=x1.y*w1; a1+=x1.z*w2; a1+=x1.w*w3;
      a2+=x2.x*w0; a2+=x2.y*w1; a2+=x2.z*w2; a2+=x2.w*w3;
      a3+=x3.x*w0; a3+=x3.y*w1; a3+=x3.z*w2; a3+=x3.w*w3;
      if (last) break;
      d4+=4; w0=nw0; w1=nw1; w2=nw2; w3=nw3;
    }
    row[r0+0][col]=tanhf(a0); row[r0+1][col]=tanhf(a1);
    row[r0+2][col]=tanhf(a2); row[r0+3][col]=tanhf(a3);
  }
  __syncthreads();
  // ================= MLP2: tanh(h1@W2+b2) -> row2, prefetched =================
  {
    const float bb = b2[col];
    a0=bb; a1=bb; a2=bb; a3=bb;
    float w0=W2[0*HH+col], w1=W2[1*HH+col], w2=W2[2*HH+col], w3=W2[3*HH+col];
    int d4=0;
    for (;;){
      const bool last = (d4+4>=HH);
      float nw0,nw1,nw2,nw3;
      if (!last){
        nw0=W2[(d4+4)*HH+col]; nw1=W2[(d4+5)*HH+col];
        nw2=W2[(d4+6)*HH+col]; nw3=W2[(d4+7)*HH+col];
      }
      float4 x0=*(const float4*)&row[r0+0][d4];
      float4 x1=*(const float4*)&row[r0+1][d4];
      float4 x2=*(const float4*)&row[r0+2][d4];
      float4 x3=*(const float4*)&row[r0+3][d4];
      a0+=x0.x*w0; a0+=x0.y*w1; a0+=x0.z*w2; a0+=x0.w*w3;
      a1+=x1.x*w0; a1+=x1.y*w1; a1+=x1.z*w2; a1+=x1.w*w3;
      a2+=x2.x*w0; a2+=x2.y*w1; a2+=x2.z*w2; a2+=x2.w*w3;
      a3+=x3.x*w0; a3+=x3.y*w1; a3+=x3.z*w2; a3+=x3.w*w3;
      if (last) break;
      d4+=4; w0=nw0; w1=nw1; w2=nw2; w3=nw3;
    }
    row2[r0+0][col]=tanhf(a0); row2[r0+1][col]=tanhf(a1);
    row2[r0+2][col]=tanhf(a2); row2[r0+3][col]=tanhf(a3);
  }
  __syncthreads();
  // ================= MLP3: gt = h2@W3+b3 (one output/thread), prefetched =====
  {
    const int c3 = t & 63, rr = t >> 6;
    float a = b3[c3];
    float w0=W3[0*DD+c3], w1=W3[1*DD+c3], w2=W3[2*DD+c3], w3=W3[3*DD+c3];
    int dp=0;
    for (;;){
      const bool last = (dp+4>=HH);
      float nw0,nw1,nw2,nw3;
      if (!last){
        nw0=W3[(dp+4)*DD+c3]; nw1=W3[(dp+5)*DD+c3];
        nw2=W3[(dp+6)*DD+c3]; nw3=W3[(dp+7)*DD+c3];
      }
      float4 h=*(const float4*)&row2[rr][dp];
      a+=h.x*w0; a+=h.y*w1; a+=h.z*w2; a+=h.w*w3;
      if (last) break;
      dp+=4; w0=nw0; w1=nw1; w2=nw2; w3=nw3;
    }
    sgt[rr][c3] = a;
  }

  // ---- codebook -> registers: thread (col,rh) holds C[col][rh*32..rh*32+31] ----
  float creg[32];
  #pragma unroll 1
  for (int cc=0; cc<4; ++cc){
    __syncthreads();                 // protect stg reuse (and fences sgt on cc=0)
    #pragma unroll
    for (int q=0;q<2;++q){
      int f=q*NT+t;                  // float4 index within 64x64 chunk
      float4 v=((const float4*)Cg)[cc*1024+f];
      int cl=f>>4, d0=(f&15)*4;
      stg[cl][d0+0]=v.x; stg[cl][d0+1]=v.y; stg[cl][d0+2]=v.z; stg[cl][d0+3]=v.w;
    }
    __syncthreads();
    if ((col>>6)==cc){
      #pragma unroll
      for (int j=0;j<32;++j) creg[j]=stg[col&63][rh*32+j];
    }
  }
  __syncthreads();

  // ---- distance partials: thread (col,rh) does half the d-range for all rows ----
  #pragma unroll 1
  for (int r=0;r<ROWS;++r){
    float p=0.f;
    #pragma unroll
    for (int d4=0; d4<32; d4+=4){
      float4 s4 = *(const float4*)&sgt[r][rh*32+d4];
      float df;
      df=s4.x-creg[d4+0]; p+=df*df;
      df=s4.y-creg[d4+1]; p+=df*df;
      df=s4.z-creg[d4+2]; p+=df*df;
      df=s4.w-creg[d4+3]; p+=df*df;
    }
    sp[rh*2048 + r*256 + col] = p;
  }
  __syncthreads();

  // ---- wave-local finalize: wave wv owns row nw, no barriers ----
  const int flag = sh_flag;
  uint32_t ka0,ka1;
  tf2x32(0u,(uint32_t)seedp[0],0u,0u,ka0,ka1);   // partitionable split: k_rng

  // carry index (one-hot argmax)
  int kv=0x7fffffff;
  if (isfinite(ksq.x)&&ksq.x>0.5f) kv=4*lane+0;
  if (isfinite(ksq.y)&&ksq.y>0.5f&&4*lane+1<kv) kv=4*lane+1;
  if (isfinite(ksq.z)&&ksq.z>0.5f&&4*lane+2<kv) kv=4*lane+2;
  if (isfinite(ksq.w)&&ksq.w>0.5f&&4*lane+3<kv) kv=4*lane+3;
  { unsigned long long bl=__ballot(kv!=0x7fffffff);
    if (bl){ int src=(int)__builtin_ctzll(bl); kv=__shfl(kv,src,64); } else kv=0; }
  const int kidx = kv;
  const float4 trq=((const float4*)tr)[(size_t)nw*(KK*KK/4)+(size_t)kidx*(KK/4)+lane];

  // VQ argmin (first-index tie-break)
  float4 p0 = *(const float4*)&sp[       wv*256 + 4*lane];
  float4 p1 = *(const float4*)&sp[2048 + wv*256 + 4*lane];
  float dv = sqrtf(p0.x+p1.x); int di = 4*lane;
  { float d1=sqrtf(p0.y+p1.y); if(d1<dv){dv=d1;di=4*lane+1;}
    float d2=sqrtf(p0.z+p1.z); if(d2<dv){dv=d2;di=4*lane+2;}
    float d3=sqrtf(p0.w+p1.w); if(d3<dv){dv=d3;di=4*lane+3;} }
  #pragma unroll
  for (int m=32;m;m>>=1){
    float ov=__shfl_xor(dv,m,64); int oi=__shfl_xor(di,m,64);
    if (ov<dv||(ov==dv&&oi<di)){dv=ov;di=oi;}
  }
  const int qk=di;

  // prior normalization
  float s=((trq.x+trq.y)+trq.z)+trq.w;
  #pragma unroll
  for (int m=32;m;m>>=1) s+=__shfl_xor(s,m,64);
  float q0=trq.x/s, q1=trq.y/s, q2=trq.z/s, q3=trq.w/s;
  { bool f0=isfinite(ksq.x),f1=isfinite(ksq.y),f2=isfinite(ksq.z),f3=isfinite(ksq.w);
    if (__any(!(f0&&f1&&f2&&f3))){
      float4 sq=((const float4*)spk)[(size_t)nw*(KK/4)+lane];
      if(!f0)q0=sq.x; if(!f1)q1=sq.y; if(!f2)q2=sq.z; if(!f3)q3=sq.w;
    } }
  const float lp0=logf(q0), lp1=logf(q1), lp2=logf(q2), lp3=logf(q3);
  const int jq=qk&3;
  float lps=(jq==0)?lp0:((jq==1)?lp1:((jq==2)?lp2:lp3));
  const float logqk=__shfl(lps,qk>>2,64);

  // mask (uniform per row)
  bool m;
  if (flag) m=((const unsigned char*)maskp)[nw]!=0;
  else      m=((const uint32_t*)maskp)[nw]!=0u;

  int sel;
  if (m){ sel=qk; }
  else {
    float sc=gumbel_of(ka0,ka1,(uint32_t)(nw*KK+4*lane+0))+lp0; int si=4*lane;
    { float g=gumbel_of(ka0,ka1,(uint32_t)(nw*KK+4*lane+1))+lp1; if(g>sc){sc=g;si=4*lane+1;} }
    { float g=gumbel_of(ka0,ka1,(uint32_t)(nw*KK+4*lane+2))+lp2; if(g>sc){sc=g;si=4*lane+2;} }
    { float g=gumbel_of(ka0,ka1,(uint32_t)(nw*KK+4*lane+3))+lp3; if(g>sc){sc=g;si=4*lane+3;} }
    #pragma unroll
    for (int mm=32;mm;mm>>=1){
      float ov=__shfl_xor(sc,mm,64); int oi=__shfl_xor(si,mm,64);
      if (ov>sc||(ov==sc&&oi<si)){sc=ov;si=oi;}
    }
    sel=si;
  }

  ((float4*)out_qk)[(size_t)nw*(KK/4)+lane]=make_float4(
    (4*lane+0==qk)?1.f:0.f,(4*lane+1==qk)?1.f:0.f,
    (4*lane+2==qk)?1.f:0.f,(4*lane+3==qk)?1.f:0.f);

  const float c=Cg[(size_t)sel*DD+lane];
  out_z[(size_t)nw*DD+lane]=c;
  float df=sgt[wv][lane]-c;
  float p=df*df;
  #pragma unroll
  for (int mm=32;mm;mm>>=1) p+=__shfl_xor(p,mm,64);
  if (lane==0){
    float tt=sqrtf(p);
    float dkl=-logqk;
    out_kl[nw]=(tt+0.25f*tt)+dkl;
    out_dkl[nw]=dkl;
  }
}

extern "C" void kernel_launch(void* const* d_in, const int* in_sizes, int n_in,
                              void* d_out, int out_size, void* d_ws, size_t ws_size,
                              hipStream_t stream){
  const float* z    = (const float*)d_in[1];
  const float* ksm  = (const float*)d_in[2];
  const float* xt   = (const float*)d_in[3];
  const void*  mask = d_in[4];
  const float* tr   = (const float*)d_in[5];
  const float* spk  = (const float*)d_in[6];
  const float* W1   = (const float*)d_in[7];
  const float* b1   = (const float*)d_in[8];
  const float* W2   = (const float*)d_in[9];
  const float* b2   = (const float*)d_in[10];
  const float* W3   = (const float*)d_in[11];
  const float* b3   = (const float*)d_in[12];
  const float* C    = (const float*)d_in[13];
  const int*   seed = (const int*)d_in[14];

  float* out_z   = (float*)d_out;                // N*D
  float* out_kl  = out_z   + (size_t)NN*DD;      // N
  float* out_dkl = out_kl  + NN;                 // N
  float* out_qk  = out_dkl + NN;                 // N*K

  k_fused<<<GRID,NT,0,stream>>>(z, ksm, xt, mask, tr, spk,
                                W1, b1, W2, b2, W3, b3, C, seed,
                                out_z, out_kl, out_dkl, out_qk);
}